// Round 5
// baseline (12195.289 us; speedup 1.0000x reference)
//
#include <hip/hip_runtime.h>
#include <math.h>

// Problem constants
#define S      610
#define E      126
#define BATCH  32
#define T      2048
#define NREG   5000

#define SPAD   640            // padded state dim
#define NT     40             // N-tiles of 16 columns (whole A)
#define KCP    10             // K-chunk pairs (64 rows each; 2 K=32 MFMAs per pair)
#define GROUPS 8              // batch groups
#define PARTS  4              // blocks per group (N-split)
#define NTB    10             // N-tiles per part
#define MB     4              // batches per group
#define GQ     2              // groups per block (antiphase pipeline)
#define GPAIRS (GROUPS / GQ)  // 4
#define THREADS 640           // 10 waves; 1 N-tile per wave
#define AROW   656            // alphaq padded row stride
#define FLAGSTRIDE 16         // ints per flag (64 B padding)

typedef float f32x4 __attribute__((ext_vector_type(4)));

// ---------- fp8 e4m3 encode (HW on gfx950, sw fallback) ---------------------
__device__ __forceinline__ unsigned sw_e4m3_enc(float f) {
    if (!(f > 0.f)) return 0u;
    int e; float fr = frexpf(f, &e);
    if (e - 1 < -6) {
        int q = (int)rintf(f * 512.f);
        if (q > 7) q = 7;
        return (unsigned)q;
    }
    int m = (int)rintf(fr * 16.f) - 8;
    int EE = e - 1;
    if (m == 8) { m = 0; EE += 1; }
    if (EE > 8) { EE = 8; m = 7; }
    return (unsigned)(((EE + 7) << 3) | m);
}
__device__ __forceinline__ unsigned pack_quad(float v0, float v1, float v2, float v3) {
#if __has_builtin(__builtin_amdgcn_cvt_pk_fp8_f32)
    int w = 0;
    w = __builtin_amdgcn_cvt_pk_fp8_f32(v0, v1, w, false);
    w = __builtin_amdgcn_cvt_pk_fp8_f32(v2, v3, w, true);
    return (unsigned)w;
#else
    return sw_e4m3_enc(v0) | (sw_e4m3_enc(v1) << 8) |
           (sw_e4m3_enc(v2) << 16) | (sw_e4m3_enc(v3) << 24);
#endif
}
__device__ __forceinline__ unsigned char fp8byte(float v) {
#if __has_builtin(__builtin_amdgcn_cvt_pk_fp8_f32)
    int w = __builtin_amdgcn_cvt_pk_fp8_f32(v, v, 0, false);
    return (unsigned char)(w & 0xFF);
#else
    return (unsigned char)sw_e4m3_enc(v);
#endif
}

// ---------- prep kernels ----------------------------------------------------
__global__ void k_init(unsigned* __restrict__ maxbuf, int* __restrict__ seq) {
    maxbuf[0] = 0u;
    if (threadIdx.x < GROUPS * PARTS) seq[threadIdx.x * FLAGSTRIDE] = 0;
}

__global__ void k_max(const float* __restrict__ A, unsigned* __restrict__ maxbuf) {
    int tid = blockIdx.x * blockDim.x + threadIdx.x;
    float m = 0.f;
    for (int i = tid; i < S * S; i += gridDim.x * blockDim.x) m = fmaxf(m, A[i]);
#pragma unroll
    for (int off = 1; off < 64; off <<= 1) m = fmaxf(m, __shfl_xor(m, off, 64));
    if ((threadIdx.x & 63) == 0) atomicMax(maxbuf, __float_as_uint(m));
}

__global__ void k_scalefin(const unsigned* __restrict__ maxbuf,
                           float* __restrict__ s_out, double* __restrict__ logs_out) {
    float mx = __uint_as_float(maxbuf[0]);
    float s = 224.f / mx;
    s_out[0] = s;
    logs_out[0] = log((double)s);
}

// Pack A*s into fp8 in MFMA B-fragment order (layout verified round 3/4).
__global__ void k_pack8frag(const float* __restrict__ A, const float* __restrict__ s_in,
                            uint4* __restrict__ A8) {
    int n   = blockIdx.x;
    int kcp = blockIdx.y;
    int l   = threadIdx.x;
    float s = s_in[0];
    int j  = n * 16 + (l & 15);
    int kq = (l >> 4) * 8;
    float v[16];
#pragma unroll
    for (int h = 0; h < 2; ++h)
#pragma unroll
        for (int i = 0; i < 8; ++i) {
            int k = kcp * 64 + h * 32 + kq + i;
            v[h * 8 + i] = (k < S && j < S) ? A[k * S + j] * s : 0.f;
        }
    uint4 out;
    out.x = pack_quad(v[0],  v[1],  v[2],  v[3]);
    out.y = pack_quad(v[4],  v[5],  v[6],  v[7]);
    out.z = pack_quad(v[8],  v[9],  v[10], v[11]);
    out.w = pack_quad(v[12], v[13], v[14], v[15]);
    A8[(n * KCP + kcp) * 64 + l] = out;
}

__global__ void k_bmt(const float* __restrict__ Bm, float* __restrict__ BmT) {
    int j = threadIdx.x;
    int o = blockIdx.x;
    BmT[o * SPAD + j] = (j < S) ? Bm[j * E + o] : 0.f;
}

__global__ void k_obs(const float* __restrict__ in, int* __restrict__ obs) {
    int i = blockIdx.x * blockDim.x + threadIdx.x;
    if (i >= BATCH * T) return;
    const float2* p = (const float2*)(in + (size_t)i * E);
    int o = 0;
#pragma unroll
    for (int k = 0; k < E / 2; ++k) {
        float2 v = p[k];
        if (v.x > 0.5f) o = 2 * k;
        if (v.y > 0.5f) o = 2 * k + 1;
    }
    obs[i] = o;
}

__global__ void k_reg(const float* __restrict__ A, const int* __restrict__ rf,
                      const int* __restrict__ rt, float* __restrict__ out) {
    __shared__ float wpart[16];
    int tid = threadIdx.x;
    float s = 0.f;
    for (int i = tid; i < NREG; i += 1024)
        s += log1pf(-A[rf[i] * S + rt[i]]);
#pragma unroll
    for (int off = 1; off < 64; off <<= 1) s += __shfl_xor(s, off, 64);
    if ((tid & 63) == 0) wpart[tid >> 6] = s;
    __syncthreads();
    if (tid == 0) {
        float t = 0.f;
        for (int w = 0; w < 16; ++w) t += wpart[w];
        out[0] = t;
    }
}

// ---------- forward recursion: 4-way N-split, 2 groups per block ------------
// Block (gpair,p) owns columns [p*160,p*160+160) for groups 2*gpair, 2*gpair+1.
// Per iteration: MFMA+publish for u, then v (publish drains hide behind the
// other group's MFMA), then spin both, consume both (overlapped remote reads).
__global__ __launch_bounds__(THREADS, 1) void k_forward(
    const uint4* __restrict__ A8,
    const float* __restrict__ BmT,
    const int*   __restrict__ obs,
    const float* __restrict__ Iv,
    const double* __restrict__ logs,
    float* __restrict__ pub,        // [GROUPS][2][MB][SPAD] fp32
    float* __restrict__ pubz,       // [GROUPS][2][PARTS][MB] fp32
    int*   __restrict__ seq,        // [GROUPS*PARTS] stride FLAGSTRIDE
    double* __restrict__ ll_out)
{
    __shared__ __align__(16) unsigned char pinA[NTB * KCP * 64 * 16];   // 102400
    __shared__ __align__(16) unsigned char alphaq[GQ][MB * AROW];       // 5248
    __shared__ __align__(16) float zpart[GQ][(THREADS / 64) * MB];      // 320
    __shared__ float zsc0[MB];

    const int gpair = blockIdx.x & 3;
    const int p     = blockIdx.x >> 2;          // partners share XCD pairs
    const int tid   = threadIdx.x;
    const int wv    = tid >> 6;
    const int lane  = tid & 63;
    const int mrow  = lane & 15;
    const int quad  = lane >> 4;
    const int jj    = (p * NTB + wv) * 16;      // this wave's global column base
    int gg[GQ];
    gg[0] = gpair * 2; gg[1] = gpair * 2 + 1;

    // Pin this part's A-slice in LDS (covered by t=0 barriers).
    {
        const uint4* src = A8 + (size_t)p * NTB * KCP * 64;
        uint4* dst = (uint4*)pinA;
        for (int i = tid; i < NTB * KCP * 64; i += THREADS) dst[i] = src[i];
    }

    // ---- t = 0: full alpha0 computed locally for both groups ---------------
    double ll[GQ];
    float Ij = (tid < S) ? Iv[tid] : 0.f;
#pragma unroll
    for (int gq = 0; gq < GQ; ++gq) {
        const int b0 = gg[gq] * MB;
        int ot[MB];
#pragma unroll
        for (int m = 0; m < MB; ++m) ot[m] = obs[(b0 + m) * T];
        float v0[MB], p0[MB];
#pragma unroll
        for (int m = 0; m < MB; ++m) { v0[m] = Ij * BmT[ot[m] * SPAD + tid]; p0[m] = v0[m]; }
#pragma unroll
        for (int off = 1; off < 64; off <<= 1)
#pragma unroll
            for (int m = 0; m < MB; ++m) p0[m] += __shfl_xor(p0[m], off, 64);
        if (lane == 0) {
#pragma unroll
            for (int m = 0; m < MB; ++m) zpart[gq][wv * MB + m] = p0[m];
        }
        __syncthreads();
        ll[gq] = 0.0;
        if (tid < MB) {
            float z = 0.f;
            for (int w = 0; w < THREADS / 64; ++w) z += zpart[gq][w * MB + tid];
            ll[gq] = (double)logf(z);
            zsc0[tid] = 128.f / z;
        }
        __syncthreads();
#pragma unroll
        for (int m = 0; m < MB; ++m)
            alphaq[gq][m * AROW + tid] = fp8byte(v0[m] * zsc0[m]);
        __syncthreads();
    }

    const uint4* pin = ((const uint4*)pinA) + wv * KCP * 64 + lane;

    // ---- main recursion -----------------------------------------------------
    for (int t = 1; t < T; ++t) {
        const int par = t & 1;

        // ===== phase 1+2: MFMA + publish for each group =====
#pragma unroll
        for (int gq = 0; gq < GQ; ++gq) {
            const int g  = gg[gq];
            const int b0 = g * MB;
            int ot[MB];
#pragma unroll
            for (int m = 0; m < MB; ++m) ot[m] = obs[(b0 + m) * T + t];
            float em[MB];
            if (lane < 16) {
#pragma unroll
                for (int m = 0; m < MB; ++m) em[m] = BmT[ot[m] * SPAD + jj + mrow];
            }

            // alpha A-operand fragments (rows 4..15 zero)
            const unsigned char* aq = alphaq[gq] + mrow * AROW + quad * 8;
            long long af[2 * KCP];
#pragma unroll
            for (int kc = 0; kc < 2 * KCP; ++kc) af[kc] = 0;
            if (mrow < 4) {
#pragma unroll
                for (int kc = 0; kc < 2 * KCP; ++kc)
                    af[kc] = *(const long long*)(aq + kc * 32);
            }

            f32x4 acc0 = (f32x4)0.f, acc1 = (f32x4)0.f;
#pragma unroll
            for (int kp = 0; kp < KCP; ++kp) {
                uint4 w = pin[kp * 64];
                union { uint2 u; long long l; } c0, c1;
                c0.u = make_uint2(w.x, w.y);
                c1.u = make_uint2(w.z, w.w);
                if (kp & 1) {
                    acc1 = __builtin_amdgcn_mfma_f32_16x16x32_fp8_fp8(af[2 * kp],     c0.l, acc1, 0, 0, 0);
                    acc1 = __builtin_amdgcn_mfma_f32_16x16x32_fp8_fp8(af[2 * kp + 1], c1.l, acc1, 0, 0, 0);
                } else {
                    acc0 = __builtin_amdgcn_mfma_f32_16x16x32_fp8_fp8(af[2 * kp],     c0.l, acc0, 0, 0, 0);
                    acc0 = __builtin_amdgcn_mfma_f32_16x16x32_fp8_fp8(af[2 * kp + 1], c1.l, acc0, 0, 0, 0);
                }
            }

            // publish c*em + wave-partial z
            float* pt = pub + ((size_t)(g * 2 + par)) * (MB * SPAD);
            if (lane < 16) {
                float cem[MB], pz[MB];
#pragma unroll
                for (int m = 0; m < MB; ++m) {
                    cem[m] = (acc0[m] + acc1[m]) * em[m];
                    pt[m * SPAD + jj + mrow] = cem[m];
                    pz[m] = cem[m];
                }
#pragma unroll
                for (int off = 1; off < 16; off <<= 1)
#pragma unroll
                    for (int m = 0; m < MB; ++m) pz[m] += __shfl_xor(pz[m], off, 64);
                if (lane == 0) {
#pragma unroll
                    for (int m = 0; m < MB; ++m) zpart[gq][wv * MB + m] = pz[m];
                }
            }
            __syncthreads();   // pub stores drained per-wave; zpart ready
            if (tid == 0) {    // tail: sum partial z, publish, fence, flag
                float zs[MB];
#pragma unroll
                for (int m = 0; m < MB; ++m) zs[m] = 0.f;
                for (int w = 0; w < THREADS / 64; ++w)
#pragma unroll
                    for (int m = 0; m < MB; ++m) zs[m] += zpart[gq][w * MB + m];
                float* pzp = pubz + (g * 2 + par) * (PARTS * MB) + p * MB;
#pragma unroll
                for (int m = 0; m < MB; ++m) pzp[m] = zs[m];
                __threadfence();
                __hip_atomic_store(seq + (g * PARTS + p) * FLAGSTRIDE, t,
                                   __ATOMIC_RELEASE, __HIP_MEMORY_SCOPE_AGENT);
            }
            // no barrier here: other waves run ahead into next group's MFMA
        }

        // ===== phase 3: spin on both groups' partners =====
        if (tid < GQ * (PARTS - 1)) {
            int gq  = tid / (PARTS - 1);
            int k   = tid % (PARTS - 1);
            int prt = (p + 1 + k) & (PARTS - 1);
            const int* f = seq + (gg[gq] * PARTS + prt) * FLAGSTRIDE;
            while (__hip_atomic_load(f, __ATOMIC_ACQUIRE, __HIP_MEMORY_SCOPE_AGENT) < t) {
                __builtin_amdgcn_s_sleep(1);
            }
        }
        __syncthreads();       // all parts visible (acquire + L1 inv before barrier)

        // ===== phase 4: consume both groups (overlapped reads) =====
        float vv[GQ][MB], z[GQ][MB];
#pragma unroll
        for (int gq = 0; gq < GQ; ++gq) {
            const float* pt = pub + ((size_t)(gg[gq] * 2 + par)) * (MB * SPAD);
#pragma unroll
            for (int m = 0; m < MB; ++m) vv[gq][m] = pt[m * SPAD + tid];
            const float* pzb = pubz + (gg[gq] * 2 + par) * (PARTS * MB);
#pragma unroll
            for (int m = 0; m < MB; ++m) {
                float zz = 0.f;
#pragma unroll
                for (int p4 = 0; p4 < PARTS; ++p4) zz += pzb[p4 * MB + m];
                z[gq][m] = zz;
            }
        }
#pragma unroll
        for (int gq = 0; gq < GQ; ++gq) {
#pragma unroll
            for (int m = 0; m < MB; ++m)
                alphaq[gq][m * AROW + tid] = fp8byte(vv[gq][m] * (128.f / z[gq][m]));
            if (tid < MB) ll[gq] += (double)logf(z[gq][tid]);
        }
        __syncthreads();       // alphaq ready for next iteration
    }

    // every step's MFMA carried factor 128*s
    const double LOG128 = 4.852030263919617;
    if (p == 0 && tid < MB) {
#pragma unroll
        for (int gq = 0; gq < GQ; ++gq)
            ll_out[gg[gq] * MB + tid] = ll[gq] - 2047.0 * (logs[0] + LOG128);
    }
}

__global__ void k_final(const double* __restrict__ ll, const float* __restrict__ regsum,
                        float* __restrict__ out) {
    double s = 0.0;
    for (int b = 0; b < BATCH; ++b) s += ll[b];
    double loglik_mean = s / BATCH;
    double reg_mean = (double)regsum[0] / NREG;
    out[0] = (float)(-loglik_mean - 4.0 * reg_mean);
}

// ---------- launch ----------------------------------------------------------
extern "C" void kernel_launch(void* const* d_in, const int* in_sizes, int n_in,
                              void* d_out, int out_size, void* d_ws, size_t ws_size,
                              hipStream_t stream) {
    const float* inputs = (const float*)d_in[0];
    const float* A      = (const float*)d_in[1];
    const float* Bm     = (const float*)d_in[2];
    const float* Iv     = (const float*)d_in[3];
    const int*   rf     = (const int*)d_in[4];
    const int*   rt     = (const int*)d_in[5];

    char* ws = (char*)d_ws;
    uint4*    A8   = (uint4*)ws;                         // 409600
    float*    BmT  = (float*)(ws + 409600);              // 322560
    int*      obs  = (int*)(ws + 732160);                // 262144
    double*   ll   = (double*)(ws + 994304);             // 256
    float*    regs = (float*)(ws + 994560);
    unsigned* mx   = (unsigned*)(ws + 994564);
    float*    sbuf = (float*)(ws + 994568);
    double*   logs = (double*)(ws + 994576);             // ..994584
    float*    pub  = (float*)(ws + 994816);              // 8*2*4*640*4 = 163840
    int*      seq  = (int*)(ws + 994816 + 163840);       // 32*64 = 2048
    float*    pubz = (float*)(ws + 994816 + 163840 + 2048); // 8*2*4*4*4 = 1024

    hipLaunchKernelGGL(k_init,      dim3(1),   dim3(64),  0, stream, mx, seq);
    hipLaunchKernelGGL(k_max,       dim3(256), dim3(256), 0, stream, A, mx);
    hipLaunchKernelGGL(k_scalefin,  dim3(1),   dim3(1),   0, stream, mx, sbuf, logs);
    hipLaunchKernelGGL(k_pack8frag, dim3(NT, KCP), dim3(64), 0, stream, A, sbuf, A8);
    hipLaunchKernelGGL(k_bmt,       dim3(E),   dim3(SPAD), 0, stream, Bm, BmT);
    hipLaunchKernelGGL(k_obs,       dim3((BATCH * T + 255) / 256), dim3(256), 0, stream, inputs, obs);
    hipLaunchKernelGGL(k_reg,       dim3(1),   dim3(1024), 0, stream, A, rf, rt, regs);
    hipLaunchKernelGGL(k_forward,   dim3(GPAIRS * PARTS), dim3(THREADS), 0, stream,
                       A8, BmT, obs, Iv, logs, pub, pubz, seq, ll);
    hipLaunchKernelGGL(k_final,     dim3(1),   dim3(1),   0, stream, ll, regs, (float*)d_out);
}

// Round 6
// 10493.433 us; speedup vs baseline: 1.1622x; 1.1622x over previous
//
#include <hip/hip_runtime.h>
#include <math.h>

// Problem constants
#define S      610
#define E      126
#define BATCH  32
#define T      2048
#define NREG   5000

#define SPAD   640            // padded state dim
#define NT     40             // N-tiles of 16 columns
#define KCP    10             // K-chunk pairs (64 rows; 2 K=32 MFMAs per pair)
#define MBX    16             // batches per block == full MFMA M
#define NBLK   2              // blocks (one per 16-batch group)
#define THREADS 640           // 10 waves
#define NWAVE  10
#define TPW    4              // N-tiles per wave (tile n = wv + 10*tl)
#define PIN    14             // tiles pinned in LDS (14*10240 = 143360 B)
#define AROW   656            // alphaq row stride (bytes)

typedef float f32x4 __attribute__((ext_vector_type(4)));

// ---------- fp8 e4m3 encode (HW on gfx950, sw fallback) ---------------------
__device__ __forceinline__ unsigned sw_e4m3_enc(float f) {
    if (!(f > 0.f)) return 0u;
    int e; float fr = frexpf(f, &e);
    if (e - 1 < -6) {
        int q = (int)rintf(f * 512.f);
        if (q > 7) q = 7;
        return (unsigned)q;
    }
    int m = (int)rintf(fr * 16.f) - 8;
    int EE = e - 1;
    if (m == 8) { m = 0; EE += 1; }
    if (EE > 8) { EE = 8; m = 7; }
    return (unsigned)(((EE + 7) << 3) | m);
}
__device__ __forceinline__ unsigned pack_quad(float v0, float v1, float v2, float v3) {
#if __has_builtin(__builtin_amdgcn_cvt_pk_fp8_f32)
    int w = 0;
    w = __builtin_amdgcn_cvt_pk_fp8_f32(v0, v1, w, false);
    w = __builtin_amdgcn_cvt_pk_fp8_f32(v2, v3, w, true);
    return (unsigned)w;
#else
    return sw_e4m3_enc(v0) | (sw_e4m3_enc(v1) << 8) |
           (sw_e4m3_enc(v2) << 16) | (sw_e4m3_enc(v3) << 24);
#endif
}
__device__ __forceinline__ unsigned char fp8byte(float v) {
#if __has_builtin(__builtin_amdgcn_cvt_pk_fp8_f32)
    int w = __builtin_amdgcn_cvt_pk_fp8_f32(v, v, 0, false);
    return (unsigned char)(w & 0xFF);
#else
    return (unsigned char)sw_e4m3_enc(v);
#endif
}

// ---------- prep kernels ----------------------------------------------------
__global__ void k_init(unsigned* __restrict__ maxbuf) { maxbuf[0] = 0u; }

__global__ void k_max(const float* __restrict__ A, unsigned* __restrict__ maxbuf) {
    int tid = blockIdx.x * blockDim.x + threadIdx.x;
    float m = 0.f;
    for (int i = tid; i < S * S; i += gridDim.x * blockDim.x) m = fmaxf(m, A[i]);
#pragma unroll
    for (int off = 1; off < 64; off <<= 1) m = fmaxf(m, __shfl_xor(m, off, 64));
    if ((threadIdx.x & 63) == 0) atomicMax(maxbuf, __float_as_uint(m));
}

__global__ void k_scalefin(const unsigned* __restrict__ maxbuf,
                           float* __restrict__ s_out, double* __restrict__ logs_out) {
    float mx = __uint_as_float(maxbuf[0]);
    float s = 224.f / mx;
    s_out[0] = s;
    logs_out[0] = log((double)s);
}

// Pack A*s into fp8 in MFMA B-fragment order (layout verified rounds 3-5).
__global__ void k_pack8frag(const float* __restrict__ A, const float* __restrict__ s_in,
                            uint4* __restrict__ A8) {
    int n   = blockIdx.x;
    int kcp = blockIdx.y;
    int l   = threadIdx.x;
    float s = s_in[0];
    int j  = n * 16 + (l & 15);
    int kq = (l >> 4) * 8;
    float v[16];
#pragma unroll
    for (int h = 0; h < 2; ++h)
#pragma unroll
        for (int i = 0; i < 8; ++i) {
            int k = kcp * 64 + h * 32 + kq + i;
            v[h * 8 + i] = (k < S && j < S) ? A[k * S + j] * s : 0.f;
        }
    uint4 out;
    out.x = pack_quad(v[0],  v[1],  v[2],  v[3]);
    out.y = pack_quad(v[4],  v[5],  v[6],  v[7]);
    out.z = pack_quad(v[8],  v[9],  v[10], v[11]);
    out.w = pack_quad(v[12], v[13], v[14], v[15]);
    A8[(n * KCP + kcp) * 64 + l] = out;
}

__global__ void k_bmt(const float* __restrict__ Bm, float* __restrict__ BmT) {
    int j = threadIdx.x;
    int o = blockIdx.x;
    BmT[o * SPAD + j] = (j < S) ? Bm[j * E + o] : 0.f;
}

// One-hot inputs -> observation symbols, TRANSPOSED: obsT[t*BATCH + b].
__global__ void k_obs(const float* __restrict__ in, int* __restrict__ obsT) {
    int i = blockIdx.x * blockDim.x + threadIdx.x;
    if (i >= BATCH * T) return;
    const float2* p = (const float2*)(in + (size_t)i * E);
    int o = 0;
#pragma unroll
    for (int k = 0; k < E / 2; ++k) {
        float2 v = p[k];
        if (v.x > 0.5f) o = 2 * k;
        if (v.y > 0.5f) o = 2 * k + 1;
    }
    int b = i / T, t = i % T;
    obsT[t * BATCH + b] = o;
}

__global__ void k_reg(const float* __restrict__ A, const int* __restrict__ rf,
                      const int* __restrict__ rt, float* __restrict__ out) {
    __shared__ float wpart[16];
    int tid = threadIdx.x;
    float s = 0.f;
    for (int i = tid; i < NREG; i += 1024)
        s += log1pf(-A[rf[i] * S + rt[i]]);
#pragma unroll
    for (int off = 1; off < 64; off <<= 1) s += __shfl_xor(s, off, 64);
    if ((tid & 63) == 0) wpart[tid >> 6] = s;
    __syncthreads();
    if (tid == 0) {
        float t = 0.f;
        for (int w = 0; w < 16; ++w) t += wpart[w];
        out[0] = t;
    }
}

// ---------- forward recursion: 2 blocks, 16 batches each, full N ------------
// One block per 16-batch group. alpha (fp8, x128/z) in LDS; A fp8 B-frag
// order: 14 tiles pinned in LDS, 26 streamed from L2. MFMA uses all 16 M rows.
__global__ __launch_bounds__(THREADS, 1) void k_forward(
    const uint4* __restrict__ A8,
    const float* __restrict__ BmT,
    const int*   __restrict__ obsT,   // [T][BATCH]
    const float* __restrict__ Iv,
    const double* __restrict__ logs,
    double* __restrict__ ll_out)
{
    __shared__ __align__(16) unsigned char pinA[PIN * KCP * 64 * 16];  // 143360
    __shared__ __align__(16) unsigned char alphaq[MBX * AROW];         // 10496
    __shared__ __align__(16) float zpart[NWAVE * MBX];                 // 640
    __shared__ float zsc[MBX];

    const int g    = blockIdx.x;      // group: batches g*16 .. g*16+15
    const int tid  = threadIdx.x;
    const int wv   = tid >> 6;
    const int lane = tid & 63;
    const int mrow = lane & 15;       // C column (state within tile)
    const int quad = lane >> 4;       // C row-group (batches quad*4..quad*4+3)
    const int b0   = g * MBX;

    // Pin A tiles 0..PIN-1 in LDS (covered by t=0 barriers).
    {
        uint4* dst = (uint4*)pinA;
        for (int i = tid; i < PIN * KCP * 64; i += THREADS) dst[i] = A8[i];
    }

    // ---- t = 0: alpha0 = I*em0 exact, per-batch z, quantize ----------------
    double ll = 0.0;   // thread tid<16 accumulates ll for batch b0+tid
    {
        float Ij = (tid < S) ? Iv[tid] : 0.f;
        float v0[MBX];
#pragma unroll
        for (int m = 0; m < MBX; ++m) {
            int o = obsT[b0 + m];
            v0[m] = Ij * BmT[o * SPAD + tid];
        }
        float p0[MBX];
#pragma unroll
        for (int m = 0; m < MBX; ++m) p0[m] = v0[m];
#pragma unroll
        for (int off = 1; off < 64; off <<= 1)
#pragma unroll
            for (int m = 0; m < MBX; ++m) p0[m] += __shfl_xor(p0[m], off, 64);
        if (lane == 0) {
#pragma unroll
            for (int m = 0; m < MBX; ++m) zpart[wv * MBX + m] = p0[m];
        }
        __syncthreads();
        if (tid < MBX) {
            float z = 0.f;
            for (int w = 0; w < NWAVE; ++w) z += zpart[w * MBX + tid];
            ll = (double)logf(z);
            zsc[tid] = 128.f / z;
        }
        __syncthreads();
#pragma unroll
        for (int m = 0; m < MBX; ++m)
            alphaq[m * AROW + tid] = fp8byte(v0[m] * zsc[m]);
        __syncthreads();
    }

    const unsigned char* aq = alphaq + mrow * AROW + quad * 8;

    // ---- main recursion -----------------------------------------------------
    for (int t = 1; t < T; ++t) {
        // observation symbols for my 4 batches (one 16B load)
        const int4 o4 = *(const int4*)(obsT + t * BATCH + b0 + quad * 4);
        // hoisted em loads: em[tl][r] = Bm[state j | obs of batch quad*4+r]
        float em[TPW][4];
#pragma unroll
        for (int tl = 0; tl < TPW; ++tl) {
            const int j = (wv + 10 * tl) * 16 + mrow;
            em[tl][0] = BmT[o4.x * SPAD + j];
            em[tl][1] = BmT[o4.y * SPAD + j];
            em[tl][2] = BmT[o4.z * SPAD + j];
            em[tl][3] = BmT[o4.w * SPAD + j];
        }

        // alpha A-operand fragments (all 16 rows live)
        long long af[2 * KCP];
#pragma unroll
        for (int kc = 0; kc < 2 * KCP; ++kc)
            af[kc] = *(const long long*)(aq + kc * 32);

        // MFMA: 4 tiles x 20 K-steps
        f32x4 acc[TPW];
#pragma unroll
        for (int tl = 0; tl < TPW; ++tl) acc[tl] = (f32x4)0.f;
#pragma unroll
        for (int tl = 0; tl < TPW; ++tl) {
            const int n = wv + 10 * tl;
            const uint4* bp = (n < PIN)
                ? ((const uint4*)pinA) + (size_t)n * KCP * 64 + lane
                : A8 + (size_t)n * KCP * 64 + lane;
#pragma unroll
            for (int kp = 0; kp < KCP; ++kp) {
                uint4 w = bp[kp * 64];
                union { uint2 u; long long l; } c0, c1;
                c0.u = make_uint2(w.x, w.y);
                c1.u = make_uint2(w.z, w.w);
                acc[tl] = __builtin_amdgcn_mfma_f32_16x16x32_fp8_fp8(af[2 * kp],     c0.l, acc[tl], 0, 0, 0);
                acc[tl] = __builtin_amdgcn_mfma_f32_16x16x32_fp8_fp8(af[2 * kp + 1], c1.l, acc[tl], 0, 0, 0);
            }
        }

        // epilogue: cem = c*em; partial z per batch (reduce over 16 lanes)
        float cem[TPW][4], pz[4];
#pragma unroll
        for (int r = 0; r < 4; ++r) pz[r] = 0.f;
#pragma unroll
        for (int tl = 0; tl < TPW; ++tl)
#pragma unroll
            for (int r = 0; r < 4; ++r) {
                cem[tl][r] = acc[tl][r] * em[tl][r];
                pz[r] += cem[tl][r];
            }
#pragma unroll
        for (int off = 1; off < 16; off <<= 1)
#pragma unroll
            for (int r = 0; r < 4; ++r) pz[r] += __shfl_xor(pz[r], off, 64);
        if (mrow == 0) {
#pragma unroll
            for (int r = 0; r < 4; ++r) zpart[wv * MBX + quad * 4 + r] = pz[r];
        }
        __syncthreads();                 // zpart ready; alphaq reads done
        if (tid < MBX) {
            float z = 0.f;
            for (int w = 0; w < NWAVE; ++w) z += zpart[w * MBX + tid];
            ll += (double)logf(z);
            zsc[tid] = 128.f / z;
        }
        __syncthreads();                 // zsc ready; safe to overwrite alphaq
#pragma unroll
        for (int tl = 0; tl < TPW; ++tl) {
            const int j = (wv + 10 * tl) * 16 + mrow;
#pragma unroll
            for (int r = 0; r < 4; ++r)
                alphaq[(quad * 4 + r) * AROW + j] = fp8byte(cem[tl][r] * zsc[quad * 4 + r]);
        }
        __syncthreads();                 // alphaq ready for next step
    }

    // every step's MFMA carried factor 128*s
    const double LOG128 = 4.852030263919617;
    if (tid < MBX) ll_out[b0 + tid] = ll - 2047.0 * (logs[0] + LOG128);
}

__global__ void k_final(const double* __restrict__ ll, const float* __restrict__ regsum,
                        float* __restrict__ out) {
    double s = 0.0;
    for (int b = 0; b < BATCH; ++b) s += ll[b];
    double loglik_mean = s / BATCH;
    double reg_mean = (double)regsum[0] / NREG;
    out[0] = (float)(-loglik_mean - 4.0 * reg_mean);
}

// ---------- launch ----------------------------------------------------------
extern "C" void kernel_launch(void* const* d_in, const int* in_sizes, int n_in,
                              void* d_out, int out_size, void* d_ws, size_t ws_size,
                              hipStream_t stream) {
    const float* inputs = (const float*)d_in[0];
    const float* A      = (const float*)d_in[1];
    const float* Bm     = (const float*)d_in[2];
    const float* Iv     = (const float*)d_in[3];
    const int*   rf     = (const int*)d_in[4];
    const int*   rt     = (const int*)d_in[5];

    char* ws = (char*)d_ws;
    uint4*    A8   = (uint4*)ws;                         // 409600
    float*    BmT  = (float*)(ws + 409600);              // 322560
    int*      obsT = (int*)(ws + 732160);                // 262144
    double*   ll   = (double*)(ws + 994304);             // 256
    float*    regs = (float*)(ws + 994560);
    unsigned* mx   = (unsigned*)(ws + 994564);
    float*    sbuf = (float*)(ws + 994568);
    double*   logs = (double*)(ws + 994576);             // ..994584

    hipLaunchKernelGGL(k_init,      dim3(1),   dim3(1),   0, stream, mx);
    hipLaunchKernelGGL(k_max,       dim3(256), dim3(256), 0, stream, A, mx);
    hipLaunchKernelGGL(k_scalefin,  dim3(1),   dim3(1),   0, stream, mx, sbuf, logs);
    hipLaunchKernelGGL(k_pack8frag, dim3(NT, KCP), dim3(64), 0, stream, A, sbuf, A8);
    hipLaunchKernelGGL(k_bmt,       dim3(E),   dim3(SPAD), 0, stream, Bm, BmT);
    hipLaunchKernelGGL(k_obs,       dim3((BATCH * T + 255) / 256), dim3(256), 0, stream, inputs, obsT);
    hipLaunchKernelGGL(k_reg,       dim3(1),   dim3(1024), 0, stream, A, rf, rt, regs);
    hipLaunchKernelGGL(k_forward,   dim3(NBLK), dim3(THREADS), 0, stream,
                       A8, BmT, obsT, Iv, logs, ll);
    hipLaunchKernelGGL(k_final,     dim3(1),   dim3(1),   0, stream, ll, regs, (float*)d_out);
}

// Round 7
// 9444.225 us; speedup vs baseline: 1.2913x; 1.1111x over previous
//
#include <hip/hip_runtime.h>
#include <math.h>

// Problem constants
#define S      610
#define E      126
#define BATCH  32
#define T      2048
#define NREG   5000

#define SPAD   640            // padded state dim
#define NT     40             // N-tiles of 16 columns
#define KCP    10             // K-chunk pairs (64 rows; 2 K=32 MFMAs per pair)
#define MBX    16             // batches per block == full MFMA M
#define NBLK   2              // blocks (one per 16-batch group)
#define THREADS 512           // 8 waves = exactly 2 per EU
#define NWAVE  8
#define TPW    5              // N-tiles per wave (tile n = wv + 8*tl)
#define PIN    14             // tiles pinned in LDS (14*10240 = 143360 B)
#define AROW   656            // alphaq row stride (bytes)

typedef float f32x4 __attribute__((ext_vector_type(4)));

template <int N> struct IC { static constexpr int v = N; };

// ---------- fp8 e4m3 encode (HW on gfx950, sw fallback) ---------------------
__device__ __forceinline__ unsigned sw_e4m3_enc(float f) {
    if (!(f > 0.f)) return 0u;
    int e; float fr = frexpf(f, &e);
    if (e - 1 < -6) {
        int q = (int)rintf(f * 512.f);
        if (q > 7) q = 7;
        return (unsigned)q;
    }
    int m = (int)rintf(fr * 16.f) - 8;
    int EE = e - 1;
    if (m == 8) { m = 0; EE += 1; }
    if (EE > 8) { EE = 8; m = 7; }
    return (unsigned)(((EE + 7) << 3) | m);
}
__device__ __forceinline__ unsigned pack_quad(float v0, float v1, float v2, float v3) {
#if __has_builtin(__builtin_amdgcn_cvt_pk_fp8_f32)
    int w = 0;
    w = __builtin_amdgcn_cvt_pk_fp8_f32(v0, v1, w, false);
    w = __builtin_amdgcn_cvt_pk_fp8_f32(v2, v3, w, true);
    return (unsigned)w;
#else
    return sw_e4m3_enc(v0) | (sw_e4m3_enc(v1) << 8) |
           (sw_e4m3_enc(v2) << 16) | (sw_e4m3_enc(v3) << 24);
#endif
}
__device__ __forceinline__ unsigned char fp8byte(float v) {
#if __has_builtin(__builtin_amdgcn_cvt_pk_fp8_f32)
    int w = __builtin_amdgcn_cvt_pk_fp8_f32(v, v, 0, false);
    return (unsigned char)(w & 0xFF);
#else
    return (unsigned char)sw_e4m3_enc(v);
#endif
}

// ---------- prep kernels ----------------------------------------------------
__global__ void k_init(unsigned* __restrict__ maxbuf) { maxbuf[0] = 0u; }

__global__ void k_max(const float* __restrict__ A, unsigned* __restrict__ maxbuf) {
    int tid = blockIdx.x * blockDim.x + threadIdx.x;
    float m = 0.f;
    for (int i = tid; i < S * S; i += gridDim.x * blockDim.x) m = fmaxf(m, A[i]);
#pragma unroll
    for (int off = 1; off < 64; off <<= 1) m = fmaxf(m, __shfl_xor(m, off, 64));
    if ((threadIdx.x & 63) == 0) atomicMax(maxbuf, __float_as_uint(m));
}

__global__ void k_scalefin(const unsigned* __restrict__ maxbuf,
                           float* __restrict__ s_out, double* __restrict__ logs_out) {
    float mx = __uint_as_float(maxbuf[0]);
    float s = 224.f / mx;
    s_out[0] = s;
    logs_out[0] = log((double)s);
}

// Pack A*s into fp8 in MFMA B-fragment order (layout verified rounds 3-6).
__global__ void k_pack8frag(const float* __restrict__ A, const float* __restrict__ s_in,
                            uint4* __restrict__ A8) {
    int n   = blockIdx.x;
    int kcp = blockIdx.y;
    int l   = threadIdx.x;
    float s = s_in[0];
    int j  = n * 16 + (l & 15);
    int kq = (l >> 4) * 8;
    float v[16];
#pragma unroll
    for (int h = 0; h < 2; ++h)
#pragma unroll
        for (int i = 0; i < 8; ++i) {
            int k = kcp * 64 + h * 32 + kq + i;
            v[h * 8 + i] = (k < S && j < S) ? A[k * S + j] * s : 0.f;
        }
    uint4 out;
    out.x = pack_quad(v[0],  v[1],  v[2],  v[3]);
    out.y = pack_quad(v[4],  v[5],  v[6],  v[7]);
    out.z = pack_quad(v[8],  v[9],  v[10], v[11]);
    out.w = pack_quad(v[12], v[13], v[14], v[15]);
    A8[(n * KCP + kcp) * 64 + l] = out;
}

__global__ void k_bmt(const float* __restrict__ Bm, float* __restrict__ BmT) {
    int j = threadIdx.x;
    int o = blockIdx.x;
    BmT[o * SPAD + j] = (j < S) ? Bm[j * E + o] : 0.f;
}

// One-hot inputs -> observation symbols, TRANSPOSED: obsT[t*BATCH + b].
__global__ void k_obs(const float* __restrict__ in, int* __restrict__ obsT) {
    int i = blockIdx.x * blockDim.x + threadIdx.x;
    if (i >= BATCH * T) return;
    const float2* p = (const float2*)(in + (size_t)i * E);
    int o = 0;
#pragma unroll
    for (int k = 0; k < E / 2; ++k) {
        float2 v = p[k];
        if (v.x > 0.5f) o = 2 * k;
        if (v.y > 0.5f) o = 2 * k + 1;
    }
    int b = i / T, t = i % T;
    obsT[t * BATCH + b] = o;
}

__global__ void k_reg(const float* __restrict__ A, const int* __restrict__ rf,
                      const int* __restrict__ rt, float* __restrict__ out) {
    __shared__ float wpart[16];
    int tid = threadIdx.x;
    float s = 0.f;
    for (int i = tid; i < NREG; i += 1024)
        s += log1pf(-A[rf[i] * S + rt[i]]);
#pragma unroll
    for (int off = 1; off < 64; off <<= 1) s += __shfl_xor(s, off, 64);
    if ((tid & 63) == 0) wpart[tid >> 6] = s;
    __syncthreads();
    if (tid == 0) {
        float t = 0.f;
        for (int w = 0; w < 16; ++w) t += wpart[w];
        out[0] = t;
    }
}

// ---------- forward recursion: 2 blocks, 16 batches each, full N ------------
// Address-space-pure tile paths: pinned tiles via typed __shared__ array
// (ds_read_b128), streamed tiles via global pointer (global_load_dwordx4)
// with depth-2 register prefetch. Wave-uniform compile-time path select.
__global__ __launch_bounds__(THREADS, 2) void k_forward(
    const uint4* __restrict__ A8,
    const float* __restrict__ BmT,
    const int*   __restrict__ obsT,   // [T][BATCH]
    const float* __restrict__ Iv,
    const double* __restrict__ logs,
    double* __restrict__ ll_out)
{
    __shared__ __align__(16) uint4 pinAv[PIN * KCP * 64];              // 143360
    __shared__ __align__(16) unsigned char alphaq[MBX * AROW];         // 10496
    __shared__ __align__(16) float zpart[NWAVE * MBX];                 // 512
    __shared__ float zsc[MBX];

    const int g    = blockIdx.x;      // group: batches g*16 .. g*16+15
    const int tid  = threadIdx.x;
    const int wv   = tid >> 6;
    const int lane = tid & 63;
    const int mrow = lane & 15;       // C column (state within tile)
    const int quad = lane >> 4;       // C row-group (batches quad*4..quad*4+3)
    const int b0   = g * MBX;

    // Pin A tiles 0..PIN-1 in LDS (covered by t=0 barriers).
    for (int i = tid; i < PIN * KCP * 64; i += THREADS) pinAv[i] = A8[i];

    // ---- t = 0: alpha0 = I*em0 exact, per-batch z, quantize ----------------
    double ll = 0.0;   // thread tid<16 accumulates ll for batch b0+tid
    {
        const int j1 = tid + THREADS;          // second state column
        const bool hasb = (j1 < SPAD);
        float Ia = (tid < S) ? Iv[tid] : 0.f;
        float Ib = (hasb && j1 < S) ? Iv[j1] : 0.f;
        float v0a[MBX], v0b[MBX], p0[MBX];
#pragma unroll
        for (int m = 0; m < MBX; ++m) {
            int o = obsT[b0 + m];
            v0a[m] = Ia * BmT[o * SPAD + tid];
            v0b[m] = hasb ? Ib * BmT[o * SPAD + j1] : 0.f;
            p0[m] = v0a[m] + v0b[m];
        }
#pragma unroll
        for (int off = 1; off < 64; off <<= 1)
#pragma unroll
            for (int m = 0; m < MBX; ++m) p0[m] += __shfl_xor(p0[m], off, 64);
        if (lane == 0) {
#pragma unroll
            for (int m = 0; m < MBX; ++m) zpart[wv * MBX + m] = p0[m];
        }
        __syncthreads();
        if (tid < MBX) {
            float z = 0.f;
            for (int w = 0; w < NWAVE; ++w) z += zpart[w * MBX + tid];
            ll = (double)logf(z);
            zsc[tid] = 128.f / z;
        }
        __syncthreads();
#pragma unroll
        for (int m = 0; m < MBX; ++m) {
            alphaq[m * AROW + tid] = fp8byte(v0a[m] * zsc[m]);
            if (hasb) alphaq[m * AROW + j1] = fp8byte(v0b[m] * zsc[m]);
        }
        __syncthreads();
    }

    const unsigned char* aq = alphaq + mrow * AROW + quad * 8;

    // ---- main recursion -----------------------------------------------------
    for (int t = 1; t < T; ++t) {
        // alpha A-operand fragments (LDS reads, issued first)
        long long af[2 * KCP];
#pragma unroll
        for (int kc = 0; kc < 2 * KCP; ++kc)
            af[kc] = *(const long long*)(aq + kc * 32);

        // observation symbols for my 4 batches + hoisted em loads
        const int4 o4 = *(const int4*)(obsT + t * BATCH + b0 + quad * 4);
        float em[TPW][4];
#pragma unroll
        for (int tl = 0; tl < TPW; ++tl) {
            const int j = (wv + 8 * tl) * 16 + mrow;
            em[tl][0] = BmT[o4.x * SPAD + j];
            em[tl][1] = BmT[o4.y * SPAD + j];
            em[tl][2] = BmT[o4.z * SPAD + j];
            em[tl][3] = BmT[o4.w * SPAD + j];
        }

        f32x4 acc[TPW];
#pragma unroll
        for (int tl = 0; tl < TPW; ++tl) acc[tl] = (f32x4)0.f;

        // tile work: GF = first global tl; tiles [0,GF) pinned, [GF,5) global
        auto tiles = [&](auto GFc) {
            constexpr int GF = decltype(GFc)::v;
            constexpr int NG = TPW - GF;
            uint4 gb[2][KCP];
            // prefetch first global tile (issues before any MFMA)
            {
                const uint4* gp = A8 + (size_t)(wv + 8 * GF) * KCP * 64 + lane;
#pragma unroll
                for (int kp = 0; kp < KCP; ++kp) gb[0][kp] = gp[kp * 64];
            }
            // pinned tiles from LDS (typed shared array -> ds_read_b128)
#pragma unroll
            for (int pi = 0; pi < GF; ++pi) {
                const int base = (wv + 8 * pi) * KCP * 64 + lane;
#pragma unroll
                for (int kp = 0; kp < KCP; ++kp) {
                    uint4 w = pinAv[base + kp * 64];
                    union { uint2 u; long long l; } c0, c1;
                    c0.u = make_uint2(w.x, w.y);
                    c1.u = make_uint2(w.z, w.w);
                    acc[pi] = __builtin_amdgcn_mfma_f32_16x16x32_fp8_fp8(af[2 * kp],     c0.l, acc[pi], 0, 0, 0);
                    acc[pi] = __builtin_amdgcn_mfma_f32_16x16x32_fp8_fp8(af[2 * kp + 1], c1.l, acc[pi], 0, 0, 0);
                }
            }
            // global tiles, depth-2 prefetch
#pragma unroll
            for (int gi = 0; gi < NG; ++gi) {
                if (gi + 1 < NG) {
                    const uint4* gp = A8 + (size_t)(wv + 8 * (GF + gi + 1)) * KCP * 64 + lane;
#pragma unroll
                    for (int kp = 0; kp < KCP; ++kp) gb[(gi + 1) & 1][kp] = gp[kp * 64];
                }
#pragma unroll
                for (int kp = 0; kp < KCP; ++kp) {
                    uint4 w = gb[gi & 1][kp];
                    union { uint2 u; long long l; } c0, c1;
                    c0.u = make_uint2(w.x, w.y);
                    c1.u = make_uint2(w.z, w.w);
                    acc[GF + gi] = __builtin_amdgcn_mfma_f32_16x16x32_fp8_fp8(af[2 * kp],     c0.l, acc[GF + gi], 0, 0, 0);
                    acc[GF + gi] = __builtin_amdgcn_mfma_f32_16x16x32_fp8_fp8(af[2 * kp + 1], c1.l, acc[GF + gi], 0, 0, 0);
                }
            }
        };
        if (wv < 6) tiles(IC<2>{}); else tiles(IC<1>{});

        // epilogue: cem = c*em; partial z per batch (reduce over 16 mrow lanes)
        float cem[TPW][4], pz[4];
#pragma unroll
        for (int r = 0; r < 4; ++r) pz[r] = 0.f;
#pragma unroll
        for (int tl = 0; tl < TPW; ++tl)
#pragma unroll
            for (int r = 0; r < 4; ++r) {
                cem[tl][r] = acc[tl][r] * em[tl][r];
                pz[r] += cem[tl][r];
            }
#pragma unroll
        for (int off = 1; off < 16; off <<= 1)
#pragma unroll
            for (int r = 0; r < 4; ++r) pz[r] += __shfl_xor(pz[r], off, 64);
        if (mrow == 0) {
#pragma unroll
            for (int r = 0; r < 4; ++r) zpart[wv * MBX + quad * 4 + r] = pz[r];
        }
        __syncthreads();                 // zpart ready; alphaq reads done
        if (tid < MBX) {
            float z = 0.f;
            for (int w = 0; w < NWAVE; ++w) z += zpart[w * MBX + tid];
            ll += (double)logf(z);
            zsc[tid] = 128.f / z;
        }
        __syncthreads();                 // zsc ready; safe to overwrite alphaq
        {
            const float zs0 = zsc[quad * 4 + 0];
            const float zs1 = zsc[quad * 4 + 1];
            const float zs2 = zsc[quad * 4 + 2];
            const float zs3 = zsc[quad * 4 + 3];
#pragma unroll
            for (int tl = 0; tl < TPW; ++tl) {
                const int j = (wv + 8 * tl) * 16 + mrow;
                alphaq[(quad * 4 + 0) * AROW + j] = fp8byte(cem[tl][0] * zs0);
                alphaq[(quad * 4 + 1) * AROW + j] = fp8byte(cem[tl][1] * zs1);
                alphaq[(quad * 4 + 2) * AROW + j] = fp8byte(cem[tl][2] * zs2);
                alphaq[(quad * 4 + 3) * AROW + j] = fp8byte(cem[tl][3] * zs3);
            }
        }
        __syncthreads();                 // alphaq ready for next step
    }

    // every step's MFMA carried factor 128*s
    const double LOG128 = 4.852030263919617;
    if (tid < MBX) ll_out[b0 + tid] = ll - 2047.0 * (logs[0] + LOG128);
}

__global__ void k_final(const double* __restrict__ ll, const float* __restrict__ regsum,
                        float* __restrict__ out) {
    double s = 0.0;
    for (int b = 0; b < BATCH; ++b) s += ll[b];
    double loglik_mean = s / BATCH;
    double reg_mean = (double)regsum[0] / NREG;
    out[0] = (float)(-loglik_mean - 4.0 * reg_mean);
}

// ---------- launch ----------------------------------------------------------
extern "C" void kernel_launch(void* const* d_in, const int* in_sizes, int n_in,
                              void* d_out, int out_size, void* d_ws, size_t ws_size,
                              hipStream_t stream) {
    const float* inputs = (const float*)d_in[0];
    const float* A      = (const float*)d_in[1];
    const float* Bm     = (const float*)d_in[2];
    const float* Iv     = (const float*)d_in[3];
    const int*   rf     = (const int*)d_in[4];
    const int*   rt     = (const int*)d_in[5];

    char* ws = (char*)d_ws;
    uint4*    A8   = (uint4*)ws;                         // 409600
    float*    BmT  = (float*)(ws + 409600);              // 322560
    int*      obsT = (int*)(ws + 732160);                // 262144
    double*   ll   = (double*)(ws + 994304);             // 256
    float*    regs = (float*)(ws + 994560);
    unsigned* mx   = (unsigned*)(ws + 994564);
    float*    sbuf = (float*)(ws + 994568);
    double*   logs = (double*)(ws + 994576);             // ..994584

    hipLaunchKernelGGL(k_init,      dim3(1),   dim3(1),   0, stream, mx);
    hipLaunchKernelGGL(k_max,       dim3(256), dim3(256), 0, stream, A, mx);
    hipLaunchKernelGGL(k_scalefin,  dim3(1),   dim3(1),   0, stream, mx, sbuf, logs);
    hipLaunchKernelGGL(k_pack8frag, dim3(NT, KCP), dim3(64), 0, stream, A, sbuf, A8);
    hipLaunchKernelGGL(k_bmt,       dim3(E),   dim3(SPAD), 0, stream, Bm, BmT);
    hipLaunchKernelGGL(k_obs,       dim3((BATCH * T + 255) / 256), dim3(256), 0, stream, inputs, obsT);
    hipLaunchKernelGGL(k_reg,       dim3(1),   dim3(1024), 0, stream, A, rf, rt, regs);
    hipLaunchKernelGGL(k_forward,   dim3(NBLK), dim3(THREADS), 0, stream,
                       A8, BmT, obsT, Iv, logs, ll);
    hipLaunchKernelGGL(k_final,     dim3(1),   dim3(1),   0, stream, ll, regs, (float*)d_out);
}

// Round 8
// 4367.284 us; speedup vs baseline: 2.7924x; 2.1625x over previous
//
#include <hip/hip_runtime.h>
#include <math.h>

// Problem constants
#define S      610
#define E      126
#define BATCH  32
#define T      2048
#define NREG   5000

#define SPAD   640            // padded state dim
#define NT     40             // N-tiles of 16 columns
#define NCH    5              // K-chunks of 128 (5*128 = 640)
#define MBX    16             // batches per block == full MFMA M
#define NBLK   2              // blocks (one per 16-batch group)
#define THREADS 512           // 8 waves = exactly 2 per EU
#define NWAVE  8
#define TPW    5              // tiles per wave: tile n = idx*8 + wv, idx 0..4
#define RT     3              // tiles held in registers (idx 0..2)
#define AROW   688            // alphaq row stride bytes (16B aligned, 2-way banks)

typedef float f32x4 __attribute__((ext_vector_type(4)));
typedef int   i32x8 __attribute__((ext_vector_type(8)));

union Frag { uint4 q[2]; i32x8 v; };

#define MFMA_SCALED(af, bf, acc) \
    __builtin_amdgcn_mfma_scale_f32_16x16x128_f8f6f4((af), (bf), (acc), 0, 0, \
                                                     0, 0x7F7F7F7F, 0, 0x7F7F7F7F)

// ---------- fp8 e4m3 encode (HW on gfx950, sw fallback) ---------------------
__device__ __forceinline__ unsigned sw_e4m3_enc(float f) {
    if (!(f > 0.f)) return 0u;
    int e; float fr = frexpf(f, &e);
    if (e - 1 < -6) {
        int q = (int)rintf(f * 512.f);
        if (q > 7) q = 7;
        return (unsigned)q;
    }
    int m = (int)rintf(fr * 16.f) - 8;
    int EE = e - 1;
    if (m == 8) { m = 0; EE += 1; }
    if (EE > 8) { EE = 8; m = 7; }
    return (unsigned)(((EE + 7) << 3) | m);
}
__device__ __forceinline__ unsigned pack_quad(float v0, float v1, float v2, float v3) {
#if __has_builtin(__builtin_amdgcn_cvt_pk_fp8_f32)
    int w = 0;
    w = __builtin_amdgcn_cvt_pk_fp8_f32(v0, v1, w, false);
    w = __builtin_amdgcn_cvt_pk_fp8_f32(v2, v3, w, true);
    return (unsigned)w;
#else
    return sw_e4m3_enc(v0) | (sw_e4m3_enc(v1) << 8) |
           (sw_e4m3_enc(v2) << 16) | (sw_e4m3_enc(v3) << 24);
#endif
}
__device__ __forceinline__ unsigned char fp8byte(float v) {
#if __has_builtin(__builtin_amdgcn_cvt_pk_fp8_f32)
    int w = __builtin_amdgcn_cvt_pk_fp8_f32(v, v, 0, false);
    return (unsigned char)(w & 0xFF);
#else
    return (unsigned char)sw_e4m3_enc(v);
#endif
}

// ---------- prep kernels ----------------------------------------------------
__global__ void k_init(unsigned* __restrict__ maxbuf) { maxbuf[0] = 0u; }

__global__ void k_max(const float* __restrict__ A, unsigned* __restrict__ maxbuf) {
    int tid = blockIdx.x * blockDim.x + threadIdx.x;
    float m = 0.f;
    for (int i = tid; i < S * S; i += gridDim.x * blockDim.x) m = fmaxf(m, A[i]);
#pragma unroll
    for (int off = 1; off < 64; off <<= 1) m = fmaxf(m, __shfl_xor(m, off, 64));
    if ((threadIdx.x & 63) == 0) atomicMax(maxbuf, __float_as_uint(m));
}

__global__ void k_scalefin(const unsigned* __restrict__ maxbuf,
                           float* __restrict__ s_out, double* __restrict__ logs_out) {
    float mx = __uint_as_float(maxbuf[0]);
    float s = 224.f / mx;
    s_out[0] = s;
    logs_out[0] = log((double)s);
}

// Pack A*s into fp8 for the scaled-MFMA B operand, K=128 fragments.
// Layout: A8c[((n*NCH + c)*2 + h)*64 + lane] = uint4; lane (n16=l&15, quad):
//   column j = n*16 + n16;  dword r byte p -> k = c*128 + quad*32 + h*16 + r*4 + p
// (A-operand alpha uses the SAME assumed k-map -> any permutation cancels.)
__global__ void k_pack8mx(const float* __restrict__ A, const float* __restrict__ s_in,
                          uint4* __restrict__ A8c) {
    int n = blockIdx.x;      // 0..NT-1
    int c = blockIdx.y;      // 0..NCH-1
    int l = threadIdx.x;     // 0..63
    float s = s_in[0];
    int j = n * 16 + (l & 15);
    int kb = c * 128 + (l >> 4) * 32;
#pragma unroll
    for (int h = 0; h < 2; ++h) {
        unsigned dw[4];
#pragma unroll
        for (int r = 0; r < 4; ++r) {
            float v[4];
#pragma unroll
            for (int p = 0; p < 4; ++p) {
                int k = kb + h * 16 + r * 4 + p;
                v[p] = (k < S && j < S) ? A[k * S + j] * s : 0.f;
            }
            dw[r] = pack_quad(v[0], v[1], v[2], v[3]);
        }
        A8c[((n * NCH + c) * 2 + h) * 64 + l] = make_uint4(dw[0], dw[1], dw[2], dw[3]);
    }
}

__global__ void k_bmt(const float* __restrict__ Bm, float* __restrict__ BmT) {
    int j = threadIdx.x;
    int o = blockIdx.x;
    BmT[o * SPAD + j] = (j < S) ? Bm[j * E + o] : 0.f;
}

// One-hot inputs -> observation symbols, TRANSPOSED: obsT[t*BATCH + b].
__global__ void k_obs(const float* __restrict__ in, int* __restrict__ obsT) {
    int i = blockIdx.x * blockDim.x + threadIdx.x;
    if (i >= BATCH * T) return;
    const float2* p = (const float2*)(in + (size_t)i * E);
    int o = 0;
#pragma unroll
    for (int k = 0; k < E / 2; ++k) {
        float2 v = p[k];
        if (v.x > 0.5f) o = 2 * k;
        if (v.y > 0.5f) o = 2 * k + 1;
    }
    int b = i / T, t = i % T;
    obsT[t * BATCH + b] = o;
}

__global__ void k_reg(const float* __restrict__ A, const int* __restrict__ rf,
                      const int* __restrict__ rt, float* __restrict__ out) {
    __shared__ float wpart[16];
    int tid = threadIdx.x;
    float s = 0.f;
    for (int i = tid; i < NREG; i += 1024)
        s += log1pf(-A[rf[i] * S + rt[i]]);
#pragma unroll
    for (int off = 1; off < 64; off <<= 1) s += __shfl_xor(s, off, 64);
    if ((tid & 63) == 0) wpart[tid >> 6] = s;
    __syncthreads();
    if (tid == 0) {
        float t = 0.f;
        for (int w = 0; w < 16; ++w) t += wpart[w];
        out[0] = t;
    }
}

// ---------- forward recursion: 2 blocks, 16 batches, scaled-MX fp8 MFMA -----
// Per wave: 5 N-tiles (idx*8+wv): idx 0..2 in REGISTERS, idx 3 from LDS pin,
// idx 4 streamed from L2 with chunk prefetch. K=128 MFMA at 2x fp8 rate,
// scales fixed to 1.0 -> numerics identical to plain fp8.
__global__ __launch_bounds__(THREADS, 2) void k_forward(
    const uint4* __restrict__ A8c,
    const float* __restrict__ BmT,
    const int*   __restrict__ obsT,   // [T][BATCH]
    const float* __restrict__ Iv,
    const double* __restrict__ logs,
    double* __restrict__ ll_out)
{
    __shared__ __align__(16) uint4 pinAv[8 * NCH * 2 * 64];            // 81920 B
    __shared__ __align__(16) unsigned char alphaq[MBX * AROW];         // 11008 B
    __shared__ __align__(16) float zpart[NWAVE * MBX];                 // 512 B
    __shared__ float zsc[MBX];

    const int g    = blockIdx.x;      // group: batches g*16 .. g*16+15
    const int tid  = threadIdx.x;
    const int wv   = tid >> 6;
    const int lane = tid & 63;
    const int mrow = lane & 15;
    const int quad = lane >> 4;
    const int b0   = g * MBX;

    // Pin tiles 24..31 in LDS (contiguous range of A8c).
    for (int i = tid; i < 8 * NCH * 2 * 64; i += THREADS)
        pinAv[i] = A8c[24 * NCH * 2 * 64 + i];

    // Preload tiles wv, 8+wv, 16+wv into registers (held across the t-loop).
    uint4 areg[RT][NCH][2];
#pragma unroll
    for (int rt = 0; rt < RT; ++rt)
#pragma unroll
        for (int c = 0; c < NCH; ++c)
#pragma unroll
            for (int h = 0; h < 2; ++h)
                areg[rt][c][h] = A8c[(((rt * 8 + wv) * NCH + c) * 2 + h) * 64 + lane];

    // ---- t = 0: alpha0 = I*em0 exact, per-batch z, quantize ----------------
    double ll = 0.0;   // thread tid<16 accumulates ll for batch b0+tid
    {
        const int j1 = tid + THREADS;
        const bool hasb = (j1 < SPAD);
        float Ia = (tid < S) ? Iv[tid] : 0.f;
        float Ib = (hasb && j1 < S) ? Iv[j1] : 0.f;
        float v0a[MBX], v0b[MBX], p0[MBX];
#pragma unroll
        for (int m = 0; m < MBX; ++m) {
            int o = obsT[b0 + m];
            v0a[m] = Ia * BmT[o * SPAD + tid];
            v0b[m] = hasb ? Ib * BmT[o * SPAD + j1] : 0.f;
            p0[m] = v0a[m] + v0b[m];
        }
#pragma unroll
        for (int off = 1; off < 64; off <<= 1)
#pragma unroll
            for (int m = 0; m < MBX; ++m) p0[m] += __shfl_xor(p0[m], off, 64);
        if (lane == 0) {
#pragma unroll
            for (int m = 0; m < MBX; ++m) zpart[wv * MBX + m] = p0[m];
        }
        __syncthreads();
        if (tid < MBX) {
            float z = 0.f;
            for (int w = 0; w < NWAVE; ++w) z += zpart[w * MBX + tid];
            ll = (double)logf(z);
            zsc[tid] = 128.f / z;
        }
        __syncthreads();
#pragma unroll
        for (int m = 0; m < MBX; ++m) {
            alphaq[m * AROW + tid] = fp8byte(v0a[m] * zsc[m]);
            if (hasb) alphaq[m * AROW + j1] = fp8byte(v0b[m] * zsc[m]);
        }
        __syncthreads();
    }

    const uint4* sp = A8c + (size_t)((32 + wv) * NCH * 2) * 64 + lane;  // stream tile
    const unsigned char* aqp = alphaq + mrow * AROW + quad * 32;

    // ---- main recursion -----------------------------------------------------
    for (int t = 1; t < T; ++t) {
        // stream-tile chunk 0 prefetch (global, issues first)
        uint4 gs[2][2];
        gs[0][0] = sp[0];
        gs[0][1] = sp[64];

        // alpha A-operand fragments: contiguous 32 B per lane per chunk
        Frag af[NCH];
#pragma unroll
        for (int c = 0; c < NCH; ++c) {
            af[c].q[0] = *(const uint4*)(aqp + c * 128);
            af[c].q[1] = *(const uint4*)(aqp + c * 128 + 16);
        }

        // obs + hoisted em loads (needed only in epilogue)
        const int4 o4 = *(const int4*)(obsT + t * BATCH + b0 + quad * 4);
        float em[TPW][4];
#pragma unroll
        for (int idx = 0; idx < TPW; ++idx) {
            const int j = (idx * 8 + wv) * 16 + mrow;
            em[idx][0] = BmT[o4.x * SPAD + j];
            em[idx][1] = BmT[o4.y * SPAD + j];
            em[idx][2] = BmT[o4.z * SPAD + j];
            em[idx][3] = BmT[o4.w * SPAD + j];
        }

        f32x4 acc[TPW];
#pragma unroll
        for (int idx = 0; idx < TPW; ++idx) acc[idx] = (f32x4)0.f;

#pragma unroll
        for (int c = 0; c < NCH; ++c) {
            // prefetch next stream chunk while this chunk computes
            if (c + 1 < NCH) {
                gs[(c + 1) & 1][0] = sp[((c + 1) * 2 + 0) * 64];
                gs[(c + 1) & 1][1] = sp[((c + 1) * 2 + 1) * 64];
            }
            // register tiles (idx 0..2) — zero-load operands
#pragma unroll
            for (int rt = 0; rt < RT; ++rt) {
                Frag bf;
                bf.q[0] = areg[rt][c][0];
                bf.q[1] = areg[rt][c][1];
                acc[rt] = MFMA_SCALED(af[c].v, bf.v, acc[rt]);
            }
            // LDS tile (idx 3)
            {
                Frag bf;
                bf.q[0] = pinAv[((wv * NCH + c) * 2 + 0) * 64 + lane];
                bf.q[1] = pinAv[((wv * NCH + c) * 2 + 1) * 64 + lane];
                acc[3] = MFMA_SCALED(af[c].v, bf.v, acc[3]);
            }
            // stream tile (idx 4)
            {
                Frag bf;
                bf.q[0] = gs[c & 1][0];
                bf.q[1] = gs[c & 1][1];
                acc[4] = MFMA_SCALED(af[c].v, bf.v, acc[4]);
            }
        }

        // epilogue: cem = c*em; partial z per batch (reduce over 16 mrow lanes)
        float cem[TPW][4], pz[4];
#pragma unroll
        for (int r = 0; r < 4; ++r) pz[r] = 0.f;
#pragma unroll
        for (int idx = 0; idx < TPW; ++idx)
#pragma unroll
            for (int r = 0; r < 4; ++r) {
                cem[idx][r] = acc[idx][r] * em[idx][r];
                pz[r] += cem[idx][r];
            }
#pragma unroll
        for (int off = 1; off < 16; off <<= 1)
#pragma unroll
            for (int r = 0; r < 4; ++r) pz[r] += __shfl_xor(pz[r], off, 64);
        if (mrow == 0) {
#pragma unroll
            for (int r = 0; r < 4; ++r) zpart[wv * MBX + quad * 4 + r] = pz[r];
        }
        __syncthreads();                 // zpart ready; alphaq reads done
        if (tid < MBX) {
            float z = 0.f;
            for (int w = 0; w < NWAVE; ++w) z += zpart[w * MBX + tid];
            ll += (double)logf(z);
            zsc[tid] = 128.f / z;
        }
        __syncthreads();                 // zsc ready; safe to overwrite alphaq
        {
            const float zs0 = zsc[quad * 4 + 0];
            const float zs1 = zsc[quad * 4 + 1];
            const float zs2 = zsc[quad * 4 + 2];
            const float zs3 = zsc[quad * 4 + 3];
#pragma unroll
            for (int idx = 0; idx < TPW; ++idx) {
                const int j = (idx * 8 + wv) * 16 + mrow;
                alphaq[(quad * 4 + 0) * AROW + j] = fp8byte(cem[idx][0] * zs0);
                alphaq[(quad * 4 + 1) * AROW + j] = fp8byte(cem[idx][1] * zs1);
                alphaq[(quad * 4 + 2) * AROW + j] = fp8byte(cem[idx][2] * zs2);
                alphaq[(quad * 4 + 3) * AROW + j] = fp8byte(cem[idx][3] * zs3);
            }
        }
        __syncthreads();                 // alphaq ready for next step
    }

    // every step's MFMA carried factor 128*s
    const double LOG128 = 4.852030263919617;
    if (tid < MBX) ll_out[b0 + tid] = ll - 2047.0 * (logs[0] + LOG128);
}

__global__ void k_final(const double* __restrict__ ll, const float* __restrict__ regsum,
                        float* __restrict__ out) {
    double s = 0.0;
    for (int b = 0; b < BATCH; ++b) s += ll[b];
    double loglik_mean = s / BATCH;
    double reg_mean = (double)regsum[0] / NREG;
    out[0] = (float)(-loglik_mean - 4.0 * reg_mean);
}

// ---------- launch ----------------------------------------------------------
extern "C" void kernel_launch(void* const* d_in, const int* in_sizes, int n_in,
                              void* d_out, int out_size, void* d_ws, size_t ws_size,
                              hipStream_t stream) {
    const float* inputs = (const float*)d_in[0];
    const float* A      = (const float*)d_in[1];
    const float* Bm     = (const float*)d_in[2];
    const float* Iv     = (const float*)d_in[3];
    const int*   rf     = (const int*)d_in[4];
    const int*   rt     = (const int*)d_in[5];

    char* ws = (char*)d_ws;
    uint4*    A8c  = (uint4*)ws;                         // 40*5*2*64*16 = 409600
    float*    BmT  = (float*)(ws + 409600);              // 322560
    int*      obsT = (int*)(ws + 732160);                // 262144
    double*   ll   = (double*)(ws + 994304);             // 256
    float*    regs = (float*)(ws + 994560);
    unsigned* mx   = (unsigned*)(ws + 994564);
    float*    sbuf = (float*)(ws + 994568);
    double*   logs = (double*)(ws + 994576);             // ..994584

    hipLaunchKernelGGL(k_init,     dim3(1),   dim3(1),   0, stream, mx);
    hipLaunchKernelGGL(k_max,      dim3(256), dim3(256), 0, stream, A, mx);
    hipLaunchKernelGGL(k_scalefin, dim3(1),   dim3(1),   0, stream, mx, sbuf, logs);
    hipLaunchKernelGGL(k_pack8mx,  dim3(NT, NCH), dim3(64), 0, stream, A, sbuf, A8c);
    hipLaunchKernelGGL(k_bmt,      dim3(E),   dim3(SPAD), 0, stream, Bm, BmT);
    hipLaunchKernelGGL(k_obs,      dim3((BATCH * T + 255) / 256), dim3(256), 0, stream, inputs, obsT);
    hipLaunchKernelGGL(k_reg,      dim3(1),   dim3(1024), 0, stream, A, rf, rt, regs);
    hipLaunchKernelGGL(k_forward,  dim3(NBLK), dim3(THREADS), 0, stream,
                       A8c, BmT, obsT, Iv, logs, ll);
    hipLaunchKernelGGL(k_final,    dim3(1),   dim3(1),   0, stream, ll, regs, (float*)d_out);
}